// Round 3
// baseline (131.402 us; speedup 1.0000x reference)
//
#include <hip/hip_runtime.h>

// Problem constants
#define BATCH 64
#define GH 14
#define GW 14
#define NPATCH (GH*GW)        // 196
#define M_ROWS (BATCH*NPATCH) // 12544
#define KDIM 768              // 3*16*16
#define DDIM 384              // EMBED
#define HW (224*224)

typedef __attribute__((ext_vector_type(8))) short s16x8;
typedef __attribute__((ext_vector_type(4))) float f32x4;
typedef __attribute__((ext_vector_type(4))) unsigned short u16x4;

__device__ __forceinline__ unsigned short f2bf(float f) {
    unsigned int u = __float_as_uint(f);
    u += 0x7fff + ((u >> 16) & 1);   // round-to-nearest-even
    return (unsigned short)(u >> 16);
}

__device__ __forceinline__ s16x8 cvt8(float4 lo, float4 hi) {
    s16x8 o;
    o[0] = (short)f2bf(lo.x); o[1] = (short)f2bf(lo.y);
    o[2] = (short)f2bf(lo.z); o[3] = (short)f2bf(lo.w);
    o[4] = (short)f2bf(hi.x); o[5] = (short)f2bf(hi.y);
    o[6] = (short)f2bf(hi.z); o[7] = (short)f2bf(hi.w);
    return o;
}

// ---------------- kernel 1: weight fp32 -> bf16 cast (B^T, row-major 384x768) --
__global__ __launch_bounds__(256) void wcast_kernel(const float* __restrict__ w,
                                                    unsigned short* __restrict__ W) {
    int t = blockIdx.x * 256 + threadIdx.x;   // 73728 float4s total
    float4 v = ((const float4*)w)[t];
    u16x4 o = { f2bf(v.x), f2bf(v.y), f2bf(v.z), f2bf(v.w) };
    *(u16x4*)(W + t * 4) = o;
}

// ---------------- kernel 2: fused im2col + entropy + GEMM + bias + LayerNorm --
// 392 blocks x 384 threads (6 waves), 32 rows/block, full N=384 (LN needs it).
// B is NOT staged in LDS: each wave reads its own 64-col fragment slice
// directly L2->reg, double-buffered 2 K-tiles deep (bE even tiles, bO odd).
// A goes through a tiny 4KB double-buffered LDS tile (same XOR swizzle as the
// verified kernel: slot kss holds global chunk kss^(row&7); read slot
// sw=(ks*4+quad)^(cl&7)), ONE barrier per K-step, A-loads issued 2 steps early.
// LDS total ~9KB -> occupancy VGPR-limited only.
__global__ __launch_bounds__(384, 3) void fused_kernel(const float* __restrict__ img,
                                                       const unsigned short* __restrict__ Bt,
                                                       const float* __restrict__ bias,
                                                       const float* __restrict__ gamma,
                                                       const float* __restrict__ beta,
                                                       float* __restrict__ C,
                                                       float* __restrict__ ent) {
    __shared__ __align__(16) unsigned short As0[32 * 64];   // 4 KB, even tiles
    __shared__ __align__(16) unsigned short As1[32 * 64];   // 4 KB, odd tiles
    __shared__ int hist[6][32];
    __shared__ float sred[32], sred2[32], smean[32], srstd[32];

    const int tid  = threadIdx.x;
    const int lane = tid & 63;
    const int wv   = tid >> 6;                // wave 0..5
    const int quad = lane >> 4;
    const int cl   = lane & 15;
    const int rowBase = blockIdx.x * 32;

    if (tid < 32) { sred[tid] = 0.0f; sred2[tid] = 0.0f; }

    // ---- A-staging constants (threads 0..255 own one 16B chunk per tile) ----
    // chunk: row r1=tid>>3 (0..31), K-subchunk ksg=tid&7. Per tile kn:
    // channel=(kn>>2), pixel-row block=(kn&3)*4+(ksg>>1), col=(ksg&1)*8.
    const int r1  = tid >> 3, ksg = tid & 7;
    const int sA1 = r1 * 64 + (ksg ^ (r1 & 7)) * 8;
    const float* pA1;
    {
        int p = rowBase + r1, b = p / NPATCH, n = p - b * NPATCH;
        int ph = n / GW, pw_ = n - ph * GW;
        pA1 = img + (size_t)b * (3 * HW) + (ph * 16 + (ksg >> 1)) * 224 + pw_ * 16 + (ksg & 1) * 8;
    }
    // ---- B direct-read base: this thread covers rows {wv*64+cl + j*16},
    // K-chunk quad within each 64-K tile. frag(j,ks,kn) = 8 shorts at
    // pBr + j*16*KDIM + kn*64 + ks*32.
    const unsigned short* pBr = Bt + (size_t)(wv * 64 + cl) * KDIM + quad * 8;

    // ---- prologue: issue B(0),B(1) and A(0),A(1),A(2) loads; they fly
    // during the entropy phase. ----
    s16x8 bE[8], bO[8];
#pragma unroll
    for (int j = 0; j < 4; ++j)
#pragma unroll
        for (int ks = 0; ks < 2; ++ks) {
            bE[ks * 4 + j] = *(const s16x8*)(pBr + j * (16 * KDIM) + 0 * 64 + ks * 32);
            bO[ks * 4 + j] = *(const s16x8*)(pBr + j * (16 * KDIM) + 1 * 64 + ks * 32);
        }
    float4 a0lo, a0hi, aOlo, aOhi, aElo, aEhi;
    if (tid < 256) {
        a0lo = *(const float4*)(pA1);
        a0hi = *(const float4*)(pA1 + 4);
        const float* p1 = pA1 + 1 * (4 * 224);            // tile 1 (ch0, rows 4..7)
        aOlo = *(const float4*)(p1);
        aOhi = *(const float4*)(p1 + 4);
        const float* p2 = pA1 + 2 * (4 * 224);            // tile 2 (ch0, rows 8..11)
        aElo = *(const float4*)(p2);
        aEhi = *(const float4*)(p2 + 4);
    }

    // ---- phase 1: patch entropy (wave-per-patch, 1-deep pixel prefetch) ----
    {
        const int pr  = lane >> 2;            // pixel row 0..15
        const int cc4 = (lane & 3) * 4;       // pixel col 0,4,8,12
        int p0 = rowBase + wv, b0 = p0 / NPATCH, n0i = p0 - b0 * NPATCH;
        int ph0 = n0i / GW, pw0 = n0i - ph0 * GW;
        const float* bp = img + (size_t)b0 * (3 * HW) + (ph0 * 16 + pr) * 224 + pw0 * 16 + cc4;
        float4 c0 = *(const float4*)(bp);
        float4 c1 = *(const float4*)(bp + HW);
        float4 c2 = *(const float4*)(bp + 2 * HW);
        for (int pp = wv; pp < 32; pp += 6) {
            float4 n0, n1, n2;
            if (pp + 6 < 32) {
                int p = rowBase + pp + 6, b = p / NPATCH, n = p - b * NPATCH;
                int ph = n / GW, pw_ = n - ph * GW;
                const float* np = img + (size_t)b * (3 * HW) + (ph * 16 + pr) * 224 + pw_ * 16 + cc4;
                n0 = *(const float4*)(np);
                n1 = *(const float4*)(np + HW);
                n2 = *(const float4*)(np + 2 * HW);
            }
            if (lane < 32) hist[wv][lane] = 0;
            asm volatile("s_waitcnt lgkmcnt(0)" ::: "memory");   // zero visible wave-wide
            float g[4] = { (c0.x + c1.x + c2.x) / 3.0f, (c0.y + c1.y + c2.y) / 3.0f,
                           (c0.z + c1.z + c2.z) / 3.0f, (c0.w + c1.w + c2.w) / 3.0f };
#pragma unroll
            for (int j = 0; j < 4; ++j) {
                int bin = (int)(g[j] * 31.0f);
                bin = bin < 0 ? 0 : (bin > 31 ? 31 : bin);
                atomicAdd(&hist[wv][bin], 1);
            }
            asm volatile("s_waitcnt lgkmcnt(0)" ::: "memory");   // atomics done
            float t = 0.0f;
            if (lane < 32) {
                float prb = (float)hist[wv][lane] * (1.0f / 256.0f);
                t = -prb * log2f(prb + 1e-10f);
            }
#pragma unroll
            for (int off = 32; off; off >>= 1) t += __shfl_xor(t, off);
            if (lane == 0) ent[rowBase + pp] = t * (1.0f / 5.0f);  // / log2(32)
            c0 = n0; c1 = n1; c2 = n2;
        }
    }

    // ---- stage tile 0 into As0 ----
    if (tid < 256) *(s16x8*)(As0 + sA1) = cvt8(a0lo, a0hi);
    __syncthreads();

    // ---- main K-loop: 12 tiles, 2 per unrolled h-iter, ONE barrier/step ----
    f32x4 acc[2][4] = {};
#pragma unroll
    for (int h = 0; h < 6; ++h) {
        const int t0 = 2 * h;                 // even tile (compile-time)
        // ===== even step: compute tile t0 from As0 x bE =====
        if (tid < 256) *(s16x8*)(As1 + sA1) = cvt8(aOlo, aOhi);   // tile t0+1
        if (h < 5 && tid < 256) {             // issue A(t0+3) -> aO (2-step lead)
            const int kn = t0 + 3;
            const float* p = pA1 + (kn >> 2) * HW + (kn & 3) * (4 * 224);
            aOlo = *(const float4*)(p);
            aOhi = *(const float4*)(p + 4);
        }
#pragma unroll
        for (int ks = 0; ks < 2; ++ks) {
            const int sw = (ks * 4 + quad) ^ (cl & 7);
            s16x8 af0 = *(const s16x8*)(As0 + (0 * 16 + cl) * 64 + sw * 8);
            s16x8 af1 = *(const s16x8*)(As0 + (1 * 16 + cl) * 64 + sw * 8);
#pragma unroll
            for (int j = 0; j < 4; ++j) {
                acc[0][j] = __builtin_amdgcn_mfma_f32_16x16x32_bf16(af0, bE[ks * 4 + j], acc[0][j], 0, 0, 0);
                acc[1][j] = __builtin_amdgcn_mfma_f32_16x16x32_bf16(af1, bE[ks * 4 + j], acc[1][j], 0, 0, 0);
            }
        }
        if (h < 5) {                          // reload bE <- B(t0+2)
#pragma unroll
            for (int j = 0; j < 4; ++j)
#pragma unroll
                for (int ks = 0; ks < 2; ++ks)
                    bE[ks * 4 + j] = *(const s16x8*)(pBr + j * (16 * KDIM) + (t0 + 2) * 64 + ks * 32);
        }
        __syncthreads();
        // ===== odd step: compute tile t0+1 from As1 x bO =====
        if (h < 5 && tid < 256) *(s16x8*)(As0 + sA1) = cvt8(aElo, aEhi);  // tile t0+2
        if (h < 4 && tid < 256) {             // issue A(t0+4) -> aE (2-step lead)
            const int kn = t0 + 4;
            const float* p = pA1 + (kn >> 2) * HW + (kn & 3) * (4 * 224);
            aElo = *(const float4*)(p);
            aEhi = *(const float4*)(p + 4);
        }
#pragma unroll
        for (int ks = 0; ks < 2; ++ks) {
            const int sw = (ks * 4 + quad) ^ (cl & 7);
            s16x8 af0 = *(const s16x8*)(As1 + (0 * 16 + cl) * 64 + sw * 8);
            s16x8 af1 = *(const s16x8*)(As1 + (1 * 16 + cl) * 64 + sw * 8);
#pragma unroll
            for (int j = 0; j < 4; ++j) {
                acc[0][j] = __builtin_amdgcn_mfma_f32_16x16x32_bf16(af0, bO[ks * 4 + j], acc[0][j], 0, 0, 0);
                acc[1][j] = __builtin_amdgcn_mfma_f32_16x16x32_bf16(af1, bO[ks * 4 + j], acc[1][j], 0, 0, 0);
            }
        }
        if (h < 5) {                          // reload bO <- B(t0+3)
#pragma unroll
            for (int j = 0; j < 4; ++j)
#pragma unroll
                for (int ks = 0; ks < 2; ++ks)
                    bO[ks * 4 + j] = *(const s16x8*)(pBr + j * (16 * KDIM) + (t0 + 3) * 64 + ks * 32);
        }
        if (h < 5) __syncthreads();           // last odd step needs no barrier
    }

    // ---- epilogue: bias + LayerNorm(384) + write ----
    float bv[4], gv[4], btv[4];
#pragma unroll
    for (int j = 0; j < 4; ++j) {
        int col = wv * 64 + j * 16 + cl;
        bv[j] = bias[col]; gv[j] = gamma[col]; btv[j] = beta[col];
    }

#pragma unroll
    for (int i = 0; i < 2; ++i) {
#pragma unroll
        for (int r = 0; r < 4; ++r) {
            float s1 = 0.0f, s2 = 0.0f;
#pragma unroll
            for (int j = 0; j < 4; ++j) {
                float v = acc[i][j][r] + bv[j];
                s1 += v; s2 += v * v;
            }
#pragma unroll
            for (int off = 1; off < 16; off <<= 1) {
                s1 += __shfl_xor(s1, off);
                s2 += __shfl_xor(s2, off);
            }
            if (cl == 0) {
                int row = i * 16 + quad * 4 + r;
                atomicAdd(&sred[row], s1);
                atomicAdd(&sred2[row], s2);
            }
        }
    }
    __syncthreads();
    if (tid < 32) {
        float mu  = sred[tid] * (1.0f / (float)DDIM);
        float var = sred2[tid] * (1.0f / (float)DDIM) - mu * mu;
        smean[tid] = mu;
        srstd[tid] = rsqrtf(var + 1e-5f);
    }
    __syncthreads();

#pragma unroll
    for (int i = 0; i < 2; ++i) {
#pragma unroll
        for (int r = 0; r < 4; ++r) {
            int row = i * 16 + quad * 4 + r;
            float mu = smean[row], rs = srstd[row];
            float* crow = C + (size_t)(rowBase + row) * DDIM;
#pragma unroll
            for (int j = 0; j < 4; ++j)
                crow[wv * 64 + j * 16 + cl] = (acc[i][j][r] + bv[j] - mu) * rs * gv[j] + btv[j];
        }
    }
}

extern "C" void kernel_launch(void* const* d_in, const int* in_sizes, int n_in,
                              void* d_out, int out_size, void* d_ws, size_t ws_size,
                              hipStream_t stream) {
    const float* img = (const float*)d_in[0];
    const float* pw  = (const float*)d_in[1];
    const float* pb  = (const float*)d_in[2];
    const float* gam = (const float*)d_in[3];
    const float* bet = (const float*)d_in[4];
    float* out = (float*)d_out;

    unsigned short* Wbf = (unsigned short*)d_ws;          // 384*768*2 = 589824 B
    float* ent = out + (size_t)M_ROWS * DDIM;             // entropy after x

    hipLaunchKernelGGL(wcast_kernel, dim3(288), dim3(256), 0, stream, pw, Wbf);
    hipLaunchKernelGGL(fused_kernel, dim3(392), dim3(384), 0, stream,
                       img, Wbf, pb, gam, bet, out, ent);
}

// Round 4
// 125.713 us; speedup vs baseline: 1.0453x; 1.0453x over previous
//
#include <hip/hip_runtime.h>

// Problem constants
#define BATCH 64
#define GH 14
#define GW 14
#define NPATCH (GH*GW)        // 196
#define M_ROWS (BATCH*NPATCH) // 12544
#define KDIM 768              // 3*16*16
#define DDIM 384              // EMBED
#define HW (224*224)

typedef __attribute__((ext_vector_type(8))) short s16x8;
typedef __attribute__((ext_vector_type(4))) float f32x4;
typedef __attribute__((ext_vector_type(4))) unsigned short u16x4;

__device__ __forceinline__ unsigned short f2bf(float f) {
    unsigned int u = __float_as_uint(f);
    u += 0x7fff + ((u >> 16) & 1);   // round-to-nearest-even
    return (unsigned short)(u >> 16);
}

__device__ __forceinline__ s16x8 cvt8(float4 lo, float4 hi) {
    s16x8 o;
    o[0] = (short)f2bf(lo.x); o[1] = (short)f2bf(lo.y);
    o[2] = (short)f2bf(lo.z); o[3] = (short)f2bf(lo.w);
    o[4] = (short)f2bf(hi.x); o[5] = (short)f2bf(hi.y);
    o[6] = (short)f2bf(hi.z); o[7] = (short)f2bf(hi.w);
    return o;
}

// ---------------- kernel 1: weight fp32 -> bf16 cast (B^T, row-major 384x768) --
__global__ __launch_bounds__(256) void wcast_kernel(const float* __restrict__ w,
                                                    unsigned short* __restrict__ W) {
    int t = blockIdx.x * 256 + threadIdx.x;   // 73728 float4s total
    float4 v = ((const float4*)w)[t];
    u16x4 o = { f2bf(v.x), f2bf(v.y), f2bf(v.z), f2bf(v.w) };
    *(u16x4*)(W + t * 4) = o;
}

// ---------------- kernel 2: fused im2col + entropy + GEMM + bias + LayerNorm --
// 392 blocks x 384 threads (6 waves), 32 rows/block, full N=384 (LN needs it).
// B: direct L2->reg, SINGLE-buffered (bcur, 32 VGPR). B(t+1) is reloaded into
// the same regs right after the MFMAs consume B(t); the compiler's vmcnt(0)
// drain at the end-of-step barrier guarantees it has landed for step t+1.
// (2-deep buffering is pointless under drain-at-barrier semantics and its
// 64-VGPR cost caused round-3's spill catastrophe at VGPR_Count=80.)
// A: tiny double-buffered 4KB LDS tile (XOR swizzle: slot kss holds chunk
// kss^(row&7); read slot sw=(ks*4+quad)^(cl&7)), ONE barrier per K-tile.
// Register budget ~100 VGPR -> __launch_bounds__(384,2) (128 cap) is safe.
__global__ __launch_bounds__(384, 2) void fused_kernel(const float* __restrict__ img,
                                                       const unsigned short* __restrict__ Bt,
                                                       const float* __restrict__ bias,
                                                       const float* __restrict__ gamma,
                                                       const float* __restrict__ beta,
                                                       float* __restrict__ C,
                                                       float* __restrict__ ent) {
    __shared__ __align__(16) unsigned short As0[32 * 64];   // 4 KB, even tiles
    __shared__ __align__(16) unsigned short As1[32 * 64];   // 4 KB, odd tiles
    __shared__ int hist[6][32];
    __shared__ float sred[32], sred2[32], smean[32], srstd[32];

    const int tid  = threadIdx.x;
    const int lane = tid & 63;
    const int wv   = tid >> 6;                // wave 0..5
    const int quad = lane >> 4;
    const int cl   = lane & 15;
    const int rowBase = blockIdx.x * 32;

    if (tid < 32) { sred[tid] = 0.0f; sred2[tid] = 0.0f; }

    // ---- A-staging constants (threads 0..255 own one 16B chunk per tile) ----
    // chunk: row r1=tid>>3 (0..31), K-subchunk ksg=tid&7. Per tile kn:
    // channel=(kn>>2), pixel-row block=(kn&3)*4+(ksg>>1), col=(ksg&1)*8.
    const int r1  = tid >> 3, ksg = tid & 7;
    const int sA1 = r1 * 64 + (ksg ^ (r1 & 7)) * 8;
    const float* pA1;
    {
        int p = rowBase + r1, b = p / NPATCH, n = p - b * NPATCH;
        int ph = n / GW, pw_ = n - ph * GW;
        pA1 = img + (size_t)b * (3 * HW) + (ph * 16 + (ksg >> 1)) * 224 + pw_ * 16 + (ksg & 1) * 8;
    }
    // ---- B direct-read base: this thread covers rows {wv*64+cl + j*16},
    // K-chunk quad within each 64-K tile. frag(j,ks,t) = 8 shorts at
    // pBr + j*16*KDIM + t*64 + ks*32.
    const unsigned short* pBr = Bt + (size_t)(wv * 64 + cl) * KDIM + quad * 8;

    // ---- prologue: issue B(0), A(0), A(1) loads; they fly during entropy ----
    s16x8 bcur[8];
#pragma unroll
    for (int j = 0; j < 4; ++j)
#pragma unroll
        for (int ks = 0; ks < 2; ++ks)
            bcur[ks * 4 + j] = *(const s16x8*)(pBr + j * (16 * KDIM) + ks * 32);
    float4 a0lo, a0hi, aNlo, aNhi;
    if (tid < 256) {
        a0lo = *(const float4*)(pA1);                     // tile 0
        a0hi = *(const float4*)(pA1 + 4);
        const float* p1 = pA1 + 1 * (4 * 224);            // tile 1 (ch0, rows 4..7)
        aNlo = *(const float4*)(p1);
        aNhi = *(const float4*)(p1 + 4);
    }

    // ---- phase 1: patch entropy (wave-per-patch, 1-deep pixel prefetch) ----
    {
        const int pr  = lane >> 2;            // pixel row 0..15
        const int cc4 = (lane & 3) * 4;       // pixel col 0,4,8,12
        int p0 = rowBase + wv, b0 = p0 / NPATCH, n0i = p0 - b0 * NPATCH;
        int ph0 = n0i / GW, pw0 = n0i - ph0 * GW;
        const float* bp = img + (size_t)b0 * (3 * HW) + (ph0 * 16 + pr) * 224 + pw0 * 16 + cc4;
        float4 c0 = *(const float4*)(bp);
        float4 c1 = *(const float4*)(bp + HW);
        float4 c2 = *(const float4*)(bp + 2 * HW);
        for (int pp = wv; pp < 32; pp += 6) {
            float4 n0, n1, n2;
            if (pp + 6 < 32) {
                int p = rowBase + pp + 6, b = p / NPATCH, n = p - b * NPATCH;
                int ph = n / GW, pw_ = n - ph * GW;
                const float* np = img + (size_t)b * (3 * HW) + (ph * 16 + pr) * 224 + pw_ * 16 + cc4;
                n0 = *(const float4*)(np);
                n1 = *(const float4*)(np + HW);
                n2 = *(const float4*)(np + 2 * HW);
            }
            if (lane < 32) hist[wv][lane] = 0;
            asm volatile("s_waitcnt lgkmcnt(0)" ::: "memory");   // zero visible wave-wide
            float g[4] = { (c0.x + c1.x + c2.x) / 3.0f, (c0.y + c1.y + c2.y) / 3.0f,
                           (c0.z + c1.z + c2.z) / 3.0f, (c0.w + c1.w + c2.w) / 3.0f };
#pragma unroll
            for (int j = 0; j < 4; ++j) {
                int bin = (int)(g[j] * 31.0f);
                bin = bin < 0 ? 0 : (bin > 31 ? 31 : bin);
                atomicAdd(&hist[wv][bin], 1);
            }
            asm volatile("s_waitcnt lgkmcnt(0)" ::: "memory");   // atomics done
            float t = 0.0f;
            if (lane < 32) {
                float prb = (float)hist[wv][lane] * (1.0f / 256.0f);
                t = -prb * log2f(prb + 1e-10f);
            }
#pragma unroll
            for (int off = 32; off; off >>= 1) t += __shfl_xor(t, off);
            if (lane == 0) ent[rowBase + pp] = t * (1.0f / 5.0f);  // / log2(32)
            c0 = n0; c1 = n1; c2 = n2;
        }
    }

    // ---- stage tile 0 into As0 ----
    if (tid < 256) *(s16x8*)(As0 + sA1) = cvt8(a0lo, a0hi);
    __syncthreads();

    // ---- main K-loop: 12 tiles, ONE barrier per tile ----
    // state at top of step t: As[t&1]=tile t, bcur=B(t), aN=A-pixels(t+1)
    f32x4 acc[2][4] = {};
#pragma unroll
    for (int t = 0; t < 12; ++t) {
        unsigned short* Aw = (t & 1) ? As0 : As1;        // write buf (tile t+1)
        const unsigned short* Ar = (t & 1) ? As1 : As0;  // read buf (tile t)
        if (t < 11 && tid < 256)
            *(s16x8*)(Aw + sA1) = cvt8(aNlo, aNhi);
        if (t < 10 && tid < 256) {                       // issue A(t+2)
            const int kn = t + 2;
            const float* p = pA1 + (kn >> 2) * HW + (kn & 3) * (4 * 224);
            aNlo = *(const float4*)(p);
            aNhi = *(const float4*)(p + 4);
        }
#pragma unroll
        for (int ks = 0; ks < 2; ++ks) {
            const int sw = (ks * 4 + quad) ^ (cl & 7);
            s16x8 af0 = *(const s16x8*)(Ar + (0 * 16 + cl) * 64 + sw * 8);
            s16x8 af1 = *(const s16x8*)(Ar + (1 * 16 + cl) * 64 + sw * 8);
#pragma unroll
            for (int j = 0; j < 4; ++j) {
                acc[0][j] = __builtin_amdgcn_mfma_f32_16x16x32_bf16(af0, bcur[ks * 4 + j], acc[0][j], 0, 0, 0);
                acc[1][j] = __builtin_amdgcn_mfma_f32_16x16x32_bf16(af1, bcur[ks * 4 + j], acc[1][j], 0, 0, 0);
            }
        }
        if (t < 11) {                                    // reload bcur <- B(t+1)
#pragma unroll
            for (int j = 0; j < 4; ++j)
#pragma unroll
                for (int ks = 0; ks < 2; ++ks)
                    bcur[ks * 4 + j] = *(const s16x8*)(pBr + j * (16 * KDIM) + (t + 1) * 64 + ks * 32);
            __syncthreads();                             // tile t+1 (A LDS + B regs) ready
        }
    }

    // ---- epilogue: bias + LayerNorm(384) + write ----
    float bv[4], gv[4], btv[4];
#pragma unroll
    for (int j = 0; j < 4; ++j) {
        int col = wv * 64 + j * 16 + cl;
        bv[j] = bias[col]; gv[j] = gamma[col]; btv[j] = beta[col];
    }

#pragma unroll
    for (int i = 0; i < 2; ++i) {
#pragma unroll
        for (int r = 0; r < 4; ++r) {
            float s1 = 0.0f, s2 = 0.0f;
#pragma unroll
            for (int j = 0; j < 4; ++j) {
                float v = acc[i][j][r] + bv[j];
                s1 += v; s2 += v * v;
            }
#pragma unroll
            for (int off = 1; off < 16; off <<= 1) {
                s1 += __shfl_xor(s1, off);
                s2 += __shfl_xor(s2, off);
            }
            if (cl == 0) {
                int row = i * 16 + quad * 4 + r;
                atomicAdd(&sred[row], s1);
                atomicAdd(&sred2[row], s2);
            }
        }
    }
    __syncthreads();
    if (tid < 32) {
        float mu  = sred[tid] * (1.0f / (float)DDIM);
        float var = sred2[tid] * (1.0f / (float)DDIM) - mu * mu;
        smean[tid] = mu;
        srstd[tid] = rsqrtf(var + 1e-5f);
    }
    __syncthreads();

#pragma unroll
    for (int i = 0; i < 2; ++i) {
#pragma unroll
        for (int r = 0; r < 4; ++r) {
            int row = i * 16 + quad * 4 + r;
            float mu = smean[row], rs = srstd[row];
            float* crow = C + (size_t)(rowBase + row) * DDIM;
#pragma unroll
            for (int j = 0; j < 4; ++j)
                crow[wv * 64 + j * 16 + cl] = (acc[i][j][r] + bv[j] - mu) * rs * gv[j] + btv[j];
        }
    }
}

extern "C" void kernel_launch(void* const* d_in, const int* in_sizes, int n_in,
                              void* d_out, int out_size, void* d_ws, size_t ws_size,
                              hipStream_t stream) {
    const float* img = (const float*)d_in[0];
    const float* pw  = (const float*)d_in[1];
    const float* pb  = (const float*)d_in[2];
    const float* gam = (const float*)d_in[3];
    const float* bet = (const float*)d_in[4];
    float* out = (float*)d_out;

    unsigned short* Wbf = (unsigned short*)d_ws;          // 384*768*2 = 589824 B
    float* ent = out + (size_t)M_ROWS * DDIM;             // entropy after x

    hipLaunchKernelGGL(wcast_kernel, dim3(288), dim3(256), 0, stream, pw, Wbf);
    hipLaunchKernelGGL(fused_kernel, dim3(392), dim3(384), 0, stream,
                       img, Wbf, pb, gam, bet, out, ent);
}

// Round 5
// 124.350 us; speedup vs baseline: 1.0567x; 1.0110x over previous
//
#include <hip/hip_runtime.h>

// Problem constants
#define BATCH 64
#define GH 14
#define GW 14
#define NPATCH (GH*GW)        // 196
#define M_ROWS (BATCH*NPATCH) // 12544
#define KDIM 768              // 3*16*16
#define DDIM 384              // EMBED
#define HW (224*224)

typedef __attribute__((ext_vector_type(8))) short s16x8;
typedef __attribute__((ext_vector_type(4))) float f32x4;
typedef __attribute__((ext_vector_type(4))) unsigned short u16x4;

__device__ __forceinline__ unsigned short f2bf(float f) {
    unsigned int u = __float_as_uint(f);
    u += 0x7fff + ((u >> 16) & 1);   // round-to-nearest-even
    return (unsigned short)(u >> 16);
}

__device__ __forceinline__ s16x8 cvt8(float4 lo, float4 hi) {
    s16x8 o;
    o[0] = (short)f2bf(lo.x); o[1] = (short)f2bf(lo.y);
    o[2] = (short)f2bf(lo.z); o[3] = (short)f2bf(lo.w);
    o[4] = (short)f2bf(hi.x); o[5] = (short)f2bf(hi.y);
    o[6] = (short)f2bf(hi.z); o[7] = (short)f2bf(hi.w);
    return o;
}

__device__ __forceinline__ void load_lds16(const void* g, void* l) {
    __builtin_amdgcn_global_load_lds(
        (const __attribute__((address_space(1))) unsigned int*)g,
        (__attribute__((address_space(3))) unsigned int*)l, 16, 0, 0);
}

// ---------------- kernel 1: weight fp32 -> bf16 cast (B^T, row-major 384x768) --
__global__ __launch_bounds__(256) void wcast_kernel(const float* __restrict__ w,
                                                    unsigned short* __restrict__ W) {
    int t = blockIdx.x * 256 + threadIdx.x;   // 73728 float4s total
    float4 v = ((const float4*)w)[t];
    u16x4 o = { f2bf(v.x), f2bf(v.y), f2bf(v.z), f2bf(v.w) };
    *(u16x4*)(W + t * 4) = o;
}

// ---------------- kernel 2: fused im2col + entropy + GEMM + bias + LayerNorm --
// 392 blocks x 384 threads (6 waves), 32 rows/block, full N=384 (LN needs it).
// KEY STRUCTURE (round 5): Bs slices are WAVE-PRIVATE (wave wv only ever reads
// rows [wv*64, wv*64+64)), so B is staged via global_load_lds DMA (zero VGPR,
// zero ds_write) into the wave's own slice, issued right after the wave's own
// frag reads -- overlapping MFMAs and the barrier wait. Swizzled layout is
// preserved by PRE-SWIZZLING the per-lane global source address: the slot
// term reduces to (lane&7)^(lane>>3), a per-thread constant.
// A (shared across waves) is reg-staged fp32->bf16 into a double-buffered
// 4KB LDS tile (same XOR swizzle; read slot sw=(ks*4+quad)^(cl&7)).
// ONE __syncthreads() per K-tile; its vmcnt(0) drain IS the DMA completion.
// LDS ~58KB -> 2 blocks/CU. No min-waves hint (R3's VGPR-cap disaster).
__global__ __launch_bounds__(384) void fused_kernel(const float* __restrict__ img,
                                                    const unsigned short* __restrict__ Bt,
                                                    const float* __restrict__ bias,
                                                    const float* __restrict__ gamma,
                                                    const float* __restrict__ beta,
                                                    float* __restrict__ C,
                                                    float* __restrict__ ent) {
    __shared__ __align__(16) unsigned short As0[32 * 64];   // 4 KB, even tiles
    __shared__ __align__(16) unsigned short As1[32 * 64];   // 4 KB, odd tiles
    __shared__ __align__(16) unsigned short Bs[384 * 64];   // 48 KB, 8KB/wave slice
    __shared__ int hist[6][32];
    __shared__ float sred[32], sred2[32], smean[32], srstd[32];

    const int tid  = threadIdx.x;
    const int lane = tid & 63;
    const int wv   = tid >> 6;                // wave 0..5
    const int quad = lane >> 4;
    const int cl   = lane & 15;
    const int rowBase = blockIdx.x * 32;

    if (tid < 32) { sred[tid] = 0.0f; sred2[tid] = 0.0f; }

    // ---- A-staging constants (threads 0..255 own one 16B chunk per tile) ----
    const int r1  = tid >> 3, ksg = tid & 7;
    const int sA1 = r1 * 64 + (ksg ^ (r1 & 7)) * 8;
    const float* pA1;
    {
        int p = rowBase + r1, b = p / NPATCH, n = p - b * NPATCH;
        int ph = n / GW, pw_ = n - ph * GW;
        pA1 = img + (size_t)b * (3 * HW) + (ph * 16 + (ksg >> 1)) * 224 + pw_ * 16 + (ksg & 1) * 8;
    }
    // ---- B DMA constants: wave wv stages its own slice rows [wv*64, wv*64+64)
    // as 8 chunks of 1024B. Lane l in chunk i covers row n = wv*64+i*8+(l>>3),
    // slot l&7; source chunk = (l&7)^(n&7) with n&7 == l>>3. ----
    const int l3 = lane >> 3, l7 = lane & 7;
    const unsigned short* pBsrc = Bt + (size_t)(wv * 64 + l3) * KDIM + ((l7 ^ l3) * 8);
    unsigned short* ldsB = Bs + (wv * 8) * 512 + lane * 8;   // +i*512 per chunk

    // ---- prologue: issue B(0) DMA + A(0),A(1) reg loads (fly during entropy) --
#pragma unroll
    for (int i = 0; i < 8; ++i)
        load_lds16(pBsrc + i * (8 * KDIM), ldsB + i * 512);
    float4 a0lo, a0hi, aNlo, aNhi;
    if (tid < 256) {
        a0lo = *(const float4*)(pA1);                     // tile 0
        a0hi = *(const float4*)(pA1 + 4);
        const float* p1 = pA1 + 1 * (4 * 224);            // tile 1 (ch0, rows 4..7)
        aNlo = *(const float4*)(p1);
        aNhi = *(const float4*)(p1 + 4);
    }

    // ---- phase 1: patch entropy (wave-per-patch, 1-deep pixel prefetch) ----
    {
        const int pr  = lane >> 2;            // pixel row 0..15
        const int cc4 = (lane & 3) * 4;       // pixel col 0,4,8,12
        int p0 = rowBase + wv, b0 = p0 / NPATCH, n0i = p0 - b0 * NPATCH;
        int ph0 = n0i / GW, pw0 = n0i - ph0 * GW;
        const float* bp = img + (size_t)b0 * (3 * HW) + (ph0 * 16 + pr) * 224 + pw0 * 16 + cc4;
        float4 c0 = *(const float4*)(bp);
        float4 c1 = *(const float4*)(bp + HW);
        float4 c2 = *(const float4*)(bp + 2 * HW);
        for (int pp = wv; pp < 32; pp += 6) {
            float4 n0, n1, n2;
            if (pp + 6 < 32) {
                int p = rowBase + pp + 6, b = p / NPATCH, n = p - b * NPATCH;
                int ph = n / GW, pw_ = n - ph * GW;
                const float* np = img + (size_t)b * (3 * HW) + (ph * 16 + pr) * 224 + pw_ * 16 + cc4;
                n0 = *(const float4*)(np);
                n1 = *(const float4*)(np + HW);
                n2 = *(const float4*)(np + 2 * HW);
            }
            if (lane < 32) hist[wv][lane] = 0;
            asm volatile("s_waitcnt lgkmcnt(0)" ::: "memory");   // zero visible wave-wide
            float g[4] = { (c0.x + c1.x + c2.x) / 3.0f, (c0.y + c1.y + c2.y) / 3.0f,
                           (c0.z + c1.z + c2.z) / 3.0f, (c0.w + c1.w + c2.w) / 3.0f };
#pragma unroll
            for (int j = 0; j < 4; ++j) {
                int bin = (int)(g[j] * 31.0f);
                bin = bin < 0 ? 0 : (bin > 31 ? 31 : bin);
                atomicAdd(&hist[wv][bin], 1);
            }
            asm volatile("s_waitcnt lgkmcnt(0)" ::: "memory");   // atomics done
            float t = 0.0f;
            if (lane < 32) {
                float prb = (float)hist[wv][lane] * (1.0f / 256.0f);
                t = -prb * log2f(prb + 1e-10f);
            }
#pragma unroll
            for (int off = 32; off; off >>= 1) t += __shfl_xor(t, off);
            if (lane == 0) ent[rowBase + pp] = t * (1.0f / 5.0f);  // / log2(32)
            c0 = n0; c1 = n1; c2 = n2;
        }
    }

    // ---- stage A(0) into As0; barrier drains B(0) DMA (vmcnt) + A write ----
    if (tid < 256) *(s16x8*)(As0 + sA1) = cvt8(a0lo, a0hi);
    __syncthreads();

    // ---- main K-loop: 12 tiles, ONE barrier per tile ----
    // top of step t: As[t&1]=A(t), Bs[own slice]=B(t), aN=A-pixels(t+1)
    f32x4 acc[2][4] = {};
#pragma unroll
    for (int t = 0; t < 12; ++t) {
        const unsigned short* Ar = (t & 1) ? As1 : As0;  // read buf (tile t)
        unsigned short* Aw = (t & 1) ? As0 : As1;        // write buf (tile t+1)

        // 1) read ALL fragments for tile t into regs
        s16x8 af[2][2], bf[2][4];
#pragma unroll
        for (int ks = 0; ks < 2; ++ks) {
            const int sw = (ks * 4 + quad) ^ (cl & 7);
            af[ks][0] = *(const s16x8*)(Ar + (0 * 16 + cl) * 64 + sw * 8);
            af[ks][1] = *(const s16x8*)(Ar + (1 * 16 + cl) * 64 + sw * 8);
#pragma unroll
            for (int j = 0; j < 4; ++j)
                bf[ks][j] = *(const s16x8*)(Bs + (wv * 64 + j * 16 + cl) * 64 + sw * 8);
        }
        asm volatile("s_waitcnt lgkmcnt(0)" ::: "memory");   // frags in regs
        __builtin_amdgcn_sched_barrier(0);                   // rule #18 fence

        // 2) issue B(t+1) DMA into own slice (overlaps MFMAs + barrier wait)
        if (t < 11) {
#pragma unroll
            for (int i = 0; i < 8; ++i)
                load_lds16(pBsrc + (t + 1) * 64 + i * (8 * KDIM), ldsB + i * 512);
            // 3) stage A(t+1) into the other LDS buffer
            if (tid < 256) *(s16x8*)(Aw + sA1) = cvt8(aNlo, aNhi);
        }
        // 4) issue A(t+2) pixel loads
        if (t < 10 && tid < 256) {
            const int kn = t + 2;
            const float* p = pA1 + (kn >> 2) * HW + (kn & 3) * (4 * 224);
            aNlo = *(const float4*)(p);
            aNhi = *(const float4*)(p + 4);
        }
        // 5) 16 MFMAs
#pragma unroll
        for (int ks = 0; ks < 2; ++ks)
#pragma unroll
            for (int j = 0; j < 4; ++j) {
                acc[0][j] = __builtin_amdgcn_mfma_f32_16x16x32_bf16(af[ks][0], bf[ks][j], acc[0][j], 0, 0, 0);
                acc[1][j] = __builtin_amdgcn_mfma_f32_16x16x32_bf16(af[ks][1], bf[ks][j], acc[1][j], 0, 0, 0);
            }
        // 6) barrier: vmcnt drain = B(t+1) DMA + A(t+2) loads; lgkm = A writes
        if (t < 11) __syncthreads();
    }

    // ---- epilogue: bias + LayerNorm(384) + write ----
    float bv[4], gv[4], btv[4];
#pragma unroll
    for (int j = 0; j < 4; ++j) {
        int col = wv * 64 + j * 16 + cl;
        bv[j] = bias[col]; gv[j] = gamma[col]; btv[j] = beta[col];
    }

#pragma unroll
    for (int i = 0; i < 2; ++i) {
#pragma unroll
        for (int r = 0; r < 4; ++r) {
            float s1 = 0.0f, s2 = 0.0f;
#pragma unroll
            for (int j = 0; j < 4; ++j) {
                float v = acc[i][j][r] + bv[j];
                s1 += v; s2 += v * v;
            }
#pragma unroll
            for (int off = 1; off < 16; off <<= 1) {
                s1 += __shfl_xor(s1, off);
                s2 += __shfl_xor(s2, off);
            }
            if (cl == 0) {
                int row = i * 16 + quad * 4 + r;
                atomicAdd(&sred[row], s1);
                atomicAdd(&sred2[row], s2);
            }
        }
    }
    __syncthreads();
    if (tid < 32) {
        float mu  = sred[tid] * (1.0f / (float)DDIM);
        float var = sred2[tid] * (1.0f / (float)DDIM) - mu * mu;
        smean[tid] = mu;
        srstd[tid] = rsqrtf(var + 1e-5f);
    }
    __syncthreads();

#pragma unroll
    for (int i = 0; i < 2; ++i) {
#pragma unroll
        for (int r = 0; r < 4; ++r) {
            int row = i * 16 + quad * 4 + r;
            float mu = smean[row], rs = srstd[row];
            float* crow = C + (size_t)(rowBase + row) * DDIM;
#pragma unroll
            for (int j = 0; j < 4; ++j)
                crow[wv * 64 + j * 16 + cl] = (acc[i][j][r] + bv[j] - mu) * rs * gv[j] + btv[j];
        }
    }
}

extern "C" void kernel_launch(void* const* d_in, const int* in_sizes, int n_in,
                              void* d_out, int out_size, void* d_ws, size_t ws_size,
                              hipStream_t stream) {
    const float* img = (const float*)d_in[0];
    const float* pw  = (const float*)d_in[1];
    const float* pb  = (const float*)d_in[2];
    const float* gam = (const float*)d_in[3];
    const float* bet = (const float*)d_in[4];
    float* out = (float*)d_out;

    unsigned short* Wbf = (unsigned short*)d_ws;          // 384*768*2 = 589824 B
    float* ent = out + (size_t)M_ROWS * DDIM;             // entropy after x

    hipLaunchKernelGGL(wcast_kernel, dim3(288), dim3(256), 0, stream, pw, Wbf);
    hipLaunchKernelGGL(fused_kernel, dim3(392), dim3(384), 0, stream,
                       img, Wbf, pb, gam, bet, out, ent);
}